// Round 5
// baseline (5041.633 us; speedup 1.0000x reference)
//
#include <hip/hip_runtime.h>
#include <math.h>

// LSTM anomaly scan, B=256 T=1024 I=8 H=164 O=1, WL=0, THRESH=0.1.
// One block per batch element; 512 threads = 8 waves = 2 waves/SIMD.
// CRITICAL: amdgpu_waves_per_eu(2,2) pins the allocator's occupancy target
// to 2 waves/EU (256 VGPRs/wave). Round-4 post-mortem: with only
// __launch_bounds__(512,2) (a MIN, not a target) the backend aimed at 128
// regs and spilled the weight array to scratch (WRITE_SIZE=500MB). LDS
// already limits us to 1 block/CU, so capping waves/EU at 2 costs nothing.
// Thread tid owns gate row tid (rows 0..511): 148 W_hh cols in VGPRs
// (37 float4), 16-col tail in LDS planes; W_ih in LDS planes. Rows 512..655
// (o-gate tail, 144 rows) are LDS-resident PLANE-MAJOR (w2[col][row]: lane
// stride 4 dwords = conflict-free; round-4's row-major stride 172 dwords was
// an 8-way conflict) and computed by waves 0..2 in the same k-loop, reusing
// the same v_readlane h-broadcast. One barrier per step (double-buffered
// gates); cell/h update redundant per wave; pred via DPP wave reduction.

namespace {
constexpr int kB = 256;
constexpr int kT = 1024;
constexpr int kI = 8;
constexpr int kH = 164;
constexpr int kG = 4 * kH;                 // 656
constexpr int kThreads = 512;              // 8 waves, 2 waves/SIMD
constexpr int kRegC = 37;                  // float4s of Whh in VGPRs
constexpr int kRegK = kRegC * 4;           // 148 cols
constexpr int kTailC = (kH - kRegK) / 4;   // 4 planes (cols 148..163)
constexpr int kSecRows = kG - kThreads;    // 144 rows (512..655)
constexpr int kHC = kH / 4;                // 41 Whh float4 planes per row
constexpr float kThresh = 0.1f;

__device__ __forceinline__ float rlane(float v, int l) {
    return __int_as_float(__builtin_amdgcn_readlane(__float_as_int(v), l));
}
__device__ __forceinline__ float hb(float h0, float h1, float h2, int k) {
    return (k < 64) ? rlane(h0, k)
         : (k < 128) ? rlane(h1, k - 64)
                     : rlane(h2, k - 128);
}
template <int CTRL>
__device__ __forceinline__ float dpp_add(float x) {
    int t = __builtin_amdgcn_update_dpp(0, __float_as_int(x), CTRL, 0xf, 0xf, true);
    return __int_as_float(t);
}
__device__ __forceinline__ float wave_sum(float x) {
    x += dpp_add<0x111>(x);   // row_shr:1
    x += dpp_add<0x112>(x);   // row_shr:2
    x += dpp_add<0x114>(x);   // row_shr:4
    x += dpp_add<0x118>(x);   // row_shr:8
    x += dpp_add<0x142>(x);   // row_bcast:15
    x += dpp_add<0x143>(x);   // row_bcast:31
    return rlane(x, 63);
}
__device__ __forceinline__ float sigm(float x) {
    return 1.0f / (1.0f + __expf(-x));
}
__device__ __forceinline__ float tanh_f(float x) {
    x = fminf(fmaxf(x, -15.0f), 15.0f);
    float e = __expf(2.0f * x);
    return (e - 1.0f) / (e + 1.0f);
}
} // namespace

__global__ __launch_bounds__(kThreads)
__attribute__((amdgpu_waves_per_eu(2, 2)))
void lstm_anom_kernel(
    const float* __restrict__ x,     // (B,T,I)
    const float* __restrict__ Wih,   // (4H,I)
    const float* __restrict__ Whh,   // (4H,H)
    const float* __restrict__ bih,   // (4H)
    const float* __restrict__ bhh,   // (4H)
    const float* __restrict__ Wout,  // (1,H)
    const float* __restrict__ bout,  // (1)
    float* __restrict__ out)         // preds (B,T) then flags (B,T)
{
    __shared__ float4 wih_p[2 * kG];             // 20,992 B
    __shared__ float4 wtail[kTailC * kThreads];  // 32,768 B
    __shared__ float4 w2[kHC * kSecRows];        // 94,464 B (plane-major)
    __shared__ float  gates[2][kG];              //  5,248 B  (total 153,472)

    const int tid  = threadIdx.x;
    const int lane = tid & 63;
    const int b    = blockIdx.x;

    // ---- one-time LDS staging ----
    for (int i = tid; i < 2 * kG; i += kThreads) {
        int c = (i >= kG) ? 1 : 0;
        int r = i - c * kG;
        wih_p[i] = ((const float4*)(Wih + r * kI))[c];
    }
    for (int i = tid; i < kTailC * kThreads; i += kThreads) {
        int c = i >> 9;          // /512
        int r = i & (kThreads - 1);
        wtail[i] = ((const float4*)(Whh + (size_t)r * kH + kRegK))[c];
    }
    for (int i = tid; i < kHC * kSecRows; i += kThreads) {
        int c = i / kSecRows, r = i - c * kSecRows;
        w2[i] = ((const float4*)(Whh + (size_t)(kThreads + r) * kH))[c];
    }

    // ---- primary row weights into VGPRs (148 cols) ----
    float4 wreg[kRegC];
    {
        const float4* wr = (const float4*)(Whh + (size_t)tid * kH);
        #pragma unroll
        for (int k = 0; k < kRegC; ++k) wreg[k] = wr[k];
    }
    const float bsum = bih[tid] + bhh[tid];
    const bool  is_tanh_row = (tid >= 2 * kH) && (tid < 3 * kH);

    const int   t2    = (tid < kSecRows) ? tid : 0;      // clamped 2nd row
    const float bsum2 = bih[kThreads + t2] + bhh[kThreads + t2];
    const bool  dual  = (tid >> 6) <= 2;                 // waves 0..2

    const int   u2  = (lane < kH - 128) ? (128 + lane) : (kH - 1);
    const float wo0 = Wout[lane];
    const float wo1 = Wout[64 + lane];
    const float wo2 = (128 + lane < kH) ? Wout[128 + lane] : 0.0f;
    const float bo  = bout[0];

    float vc0 = 0.f, vc1 = 0.f, vc2 = 0.f;
    float vh0 = 0.f, vh1 = 0.f, vh2 = 0.f;
    float pred = 0.f;

    float* pred_out = out + (size_t)b * kT;
    float* flag_out = out + (size_t)kB * kT + (size_t)b * kT;
    const float* xb = x + (size_t)b * kT * kI;

    float4 xa = ((const float4*)xb)[0];
    float4 xc = ((const float4*)xb)[1];

    __syncthreads();

    for (int t = 0; t < kT; ++t) {
        // prefetch x[t+1] (consumed next iter)
        const float4* nx = (const float4*)(xb + (t + 1 < kT ? (t + 1) : t) * kI);
        float4 na = nx[0];
        float4 nc = nx[1];

        const bool  anom = (t > 0) && (fabsf(pred - xa.x) > kThresh);
        const float x0e  = anom ? pred : xa.x;

        // ---- primary row W_ih part ----
        float4 wi0 = wih_p[tid];
        float4 wi1 = wih_p[kG + tid];
        float a0 = fmaf(x0e,  wi0.x, bsum);
        float a1 = xa.y * wi0.y;
        float a2 = xa.z * wi0.z;
        float a3 = xa.w * wi0.w;
        a0 = fmaf(xc.x, wi1.x, a0);
        a1 = fmaf(xc.y, wi1.y, a1);
        a2 = fmaf(xc.z, wi1.z, a2);
        a3 = fmaf(xc.w, wi1.w, a3);

        if (dual) {
            // waves 0..2: also compute second row (512 + t2) from LDS,
            // reusing the same h broadcasts.
            float4 si0 = wih_p[kThreads + t2];
            float4 si1 = wih_p[kG + kThreads + t2];
            float b0 = fmaf(x0e,  si0.x, bsum2);
            float b1 = xa.y * si0.y;
            float b2 = xa.z * si0.z;
            float b3 = xa.w * si0.w;
            b0 = fmaf(xc.x, si1.x, b0);
            b1 = fmaf(xc.y, si1.y, b1);
            b2 = fmaf(xc.z, si1.z, b2);
            b3 = fmaf(xc.w, si1.w, b3);
            #pragma unroll
            for (int kk = 0; kk < kRegC; ++kk) {
                const int k = kk * 4;
                float4 w = wreg[kk];
                float4 v = w2[kk * kSecRows + t2];
                float h0v = hb(vh0, vh1, vh2, k + 0);
                float h1v = hb(vh0, vh1, vh2, k + 1);
                float h2v = hb(vh0, vh1, vh2, k + 2);
                float h3v = hb(vh0, vh1, vh2, k + 3);
                a0 = fmaf(h0v, w.x, a0);  b0 = fmaf(h0v, v.x, b0);
                a1 = fmaf(h1v, w.y, a1);  b1 = fmaf(h1v, v.y, b1);
                a2 = fmaf(h2v, w.z, a2);  b2 = fmaf(h2v, v.z, b2);
                a3 = fmaf(h3v, w.w, a3);  b3 = fmaf(h3v, v.w, b3);
            }
            #pragma unroll
            for (int c = 0; c < kTailC; ++c) {
                const int k = kRegK + c * 4;
                float4 w = wtail[c * kThreads + tid];
                float4 v = w2[(kRegC + c) * kSecRows + t2];
                float h0v = hb(vh0, vh1, vh2, k + 0);
                float h1v = hb(vh0, vh1, vh2, k + 1);
                float h2v = hb(vh0, vh1, vh2, k + 2);
                float h3v = hb(vh0, vh1, vh2, k + 3);
                a0 = fmaf(h0v, w.x, a0);  b0 = fmaf(h0v, v.x, b0);
                a1 = fmaf(h1v, w.y, a1);  b1 = fmaf(h1v, v.y, b1);
                a2 = fmaf(h2v, w.z, a2);  b2 = fmaf(h2v, v.z, b2);
                a3 = fmaf(h3v, w.w, a3);  b3 = fmaf(h3v, v.w, b3);
            }
            const float accb = (b0 + b1) + (b2 + b3);
            if (tid < kSecRows) gates[t & 1][kThreads + tid] = sigm(accb);
        } else {
            #pragma unroll
            for (int kk = 0; kk < kRegC; ++kk) {
                const int k = kk * 4;
                float4 w = wreg[kk];
                a0 = fmaf(hb(vh0, vh1, vh2, k + 0), w.x, a0);
                a1 = fmaf(hb(vh0, vh1, vh2, k + 1), w.y, a1);
                a2 = fmaf(hb(vh0, vh1, vh2, k + 2), w.z, a2);
                a3 = fmaf(hb(vh0, vh1, vh2, k + 3), w.w, a3);
            }
            #pragma unroll
            for (int c = 0; c < kTailC; ++c) {
                const int k = kRegK + c * 4;
                float4 w = wtail[c * kThreads + tid];
                a0 = fmaf(hb(vh0, vh1, vh2, k + 0), w.x, a0);
                a1 = fmaf(hb(vh0, vh1, vh2, k + 1), w.y, a1);
                a2 = fmaf(hb(vh0, vh1, vh2, k + 2), w.z, a2);
                a3 = fmaf(hb(vh0, vh1, vh2, k + 3), w.w, a3);
            }
        }

        const float acc = (a0 + a1) + (a2 + a3);
        const float av  = is_tanh_row ? tanh_f(acc) : sigm(acc);
        gates[t & 1][tid] = av;
        __syncthreads();

        // ---- redundant cell/h update in every wave ----
        const float* gb = gates[t & 1];
        float iv0 = gb[lane],          iv1 = gb[64 + lane],          iv2 = gb[u2];
        float fv0 = gb[kH + lane],     fv1 = gb[kH + 64 + lane],     fv2 = gb[kH + u2];
        float gv0 = gb[2*kH + lane],   gv1 = gb[2*kH + 64 + lane],   gv2 = gb[2*kH + u2];
        float ov0 = gb[3*kH + lane],   ov1 = gb[3*kH + 64 + lane],   ov2 = gb[3*kH + u2];
        vc0 = fmaf(fv0, vc0, iv0 * gv0);  vh0 = ov0 * tanh_f(vc0);
        vc1 = fmaf(fv1, vc1, iv1 * gv1);  vh1 = ov1 * tanh_f(vc1);
        vc2 = fmaf(fv2, vc2, iv2 * gv2);  vh2 = ov2 * tanh_f(vc2);

        // ---- pred (identical in every wave; DPP reduce) ----
        float p = fmaf(vh0, wo0, fmaf(vh1, wo1, vh2 * wo2));
        pred = wave_sum(p) + bo;

        if (tid == 0) {
            pred_out[t] = pred;
            flag_out[t] = anom ? 1.0f : 0.0f;
        }
        xa = na;
        xc = nc;
    }
}

extern "C" void kernel_launch(void* const* d_in, const int* in_sizes, int n_in,
                              void* d_out, int out_size, void* d_ws, size_t ws_size,
                              hipStream_t stream) {
    const float* x    = (const float*)d_in[0];
    const float* Wih  = (const float*)d_in[1];
    const float* Whh  = (const float*)d_in[2];
    const float* bih  = (const float*)d_in[3];
    const float* bhh  = (const float*)d_in[4];
    const float* Wout = (const float*)d_in[5];
    const float* bout = (const float*)d_in[6];
    lstm_anom_kernel<<<dim3(kB), dim3(kThreads), 0, stream>>>(
        x, Wih, Whh, bih, bhh, Wout, bout, (float*)d_out);
}

// Round 6
// 4330.382 us; speedup vs baseline: 1.1642x; 1.1642x over previous
//
#include <hip/hip_runtime.h>
#include <math.h>

// LSTM anomaly scan, B=256 T=1024 I=8 H=164 O=1, WL=0, THRESH=0.1.
// One block per batch element; 256 threads = 4 waves = 1 wave/SIMD =
// 1 block/CU, so the per-wave register budget is the FULL 512 (no-spill
// ~450). Rounds 2-5 post-mortem: at 2-3 waves/SIMD the weight array never
// fit the allocator's budget (remat from L2 / scratch spill / AGPR
// shuffling). Here demand ~410 < 450 with occupancy pinned via
// amdgpu_waves_per_eu(1,1) (no __launch_bounds__, which may interfere).
// Thread t owns gate rows t and 256+t in VGPRs (82 float4 = 328 regs);
// rows 512..655 (o-gate tail) are LDS plane-major, 36 per wave (row3 =
// 512 + wave*36 + lane, lanes 0..35) so ALL waves carry equal load (round
// 4/5's dual-wave imbalance made SIMD0-2 the 2x hot path). Each of the 164
// v_readlane h-broadcasts now feeds 3 FMAs. One barrier per step
// (double-buffered gates); cell/h update redundant per wave (units lane,
// 64+lane, 128+lane); pred via DPP wave reduction (deterministic across
// waves).

namespace {
constexpr int kB = 256;
constexpr int kT = 1024;
constexpr int kI = 8;
constexpr int kH = 164;
constexpr int kG = 4 * kH;                 // 656
constexpr int kThreads = 256;              // 4 waves, 1 wave/SIMD
constexpr int kHC = kH / 4;                // 41 float4 planes per row
constexpr int kW2 = kG - 2 * kThreads;     // 144 third rows (512..655)
constexpr int kPerWave = kW2 / 4;          // 36 third rows per wave
constexpr float kThresh = 0.1f;

__device__ __forceinline__ float rlane(float v, int l) {
    return __int_as_float(__builtin_amdgcn_readlane(__float_as_int(v), l));
}
__device__ __forceinline__ float hb(float h0, float h1, float h2, int k) {
    return (k < 64) ? rlane(h0, k)
         : (k < 128) ? rlane(h1, k - 64)
                     : rlane(h2, k - 128);
}
template <int CTRL>
__device__ __forceinline__ float dpp_add(float x) {
    int t = __builtin_amdgcn_update_dpp(0, __float_as_int(x), CTRL, 0xf, 0xf, true);
    return __int_as_float(t);
}
__device__ __forceinline__ float wave_sum(float x) {
    x += dpp_add<0x111>(x);   // row_shr:1
    x += dpp_add<0x112>(x);   // row_shr:2
    x += dpp_add<0x114>(x);   // row_shr:4
    x += dpp_add<0x118>(x);   // row_shr:8
    x += dpp_add<0x142>(x);   // row_bcast:15
    x += dpp_add<0x143>(x);   // row_bcast:31
    return rlane(x, 63);
}
__device__ __forceinline__ float sigm(float x) {
    return 1.0f / (1.0f + __expf(-x));
}
__device__ __forceinline__ float tanh_f(float x) {
    x = fminf(fmaxf(x, -15.0f), 15.0f);
    float e = __expf(2.0f * x);
    return (e - 1.0f) / (e + 1.0f);
}
} // namespace

__global__
__attribute__((amdgpu_flat_work_group_size(kThreads, kThreads),
               amdgpu_waves_per_eu(1, 1)))
void lstm_anom_kernel(
    const float* __restrict__ x,     // (B,T,I)
    const float* __restrict__ Wih,   // (4H,I)
    const float* __restrict__ Whh,   // (4H,H)
    const float* __restrict__ bih,   // (4H)
    const float* __restrict__ bhh,   // (4H)
    const float* __restrict__ Wout,  // (1,H)
    const float* __restrict__ bout,  // (1)
    float* __restrict__ out)         // preds (B,T) then flags (B,T)
{
    __shared__ float4 wih_p[2 * kG];        // 20,992 B
    __shared__ float4 w2[kHC * kW2];        // 94,464 B (plane-major [c][row])
    __shared__ float  gates[2][kG];         //  5,248 B   (total ~120.8 KB)

    const int tid  = threadIdx.x;
    const int lane = tid & 63;
    const int wav  = tid >> 6;              // 0..3
    const int b    = blockIdx.x;

    // ---- one-time LDS staging ----
    for (int i = tid; i < 2 * kG; i += kThreads) {
        int c = (i >= kG) ? 1 : 0;
        int r = i - c * kG;
        wih_p[i] = ((const float4*)(Wih + r * kI))[c];
    }
    for (int i = tid; i < kHC * kW2; i += kThreads) {
        int c = i / kW2, r = i - c * kW2;
        w2[i] = ((const float4*)(Whh + (size_t)(2 * kThreads + r) * kH))[c];
    }

    // ---- two primary rows into VGPRs (82 float4 = 328 regs) ----
    const int r0 = tid;
    const int r1 = kThreads + tid;
    float4 wreg0[kHC], wreg1[kHC];
    {
        const float4* wr0 = (const float4*)(Whh + (size_t)r0 * kH);
        const float4* wr1 = (const float4*)(Whh + (size_t)r1 * kH);
        #pragma unroll
        for (int k = 0; k < kHC; ++k) wreg0[k] = wr0[k];
        #pragma unroll
        for (int k = 0; k < kHC; ++k) wreg1[k] = wr1[k];
    }

    // third row: 36 per wave, lanes 0..35 active (clamped for the rest)
    const int  li3   = (lane < kPerWave) ? lane : (kPerWave - 1);
    const int  i3    = wav * kPerWave + li3;        // 0..143
    const int  r3    = 2 * kThreads + i3;           // 512..655
    const bool act3  = (lane < kPerWave);

    const float bsum0 = bih[r0] + bhh[r0];
    const float bsum1 = bih[r1] + bhh[r1];
    const float bsum3 = bih[r3] + bhh[r3];
    // row0 in [0,512): i/f -> sigmoid. row1 in [256,512): tanh iff in [328,492).
    const bool  tanh1 = (r1 >= 2 * kH) && (r1 < 3 * kH);
    // row3 in [512,656): o-gate -> sigmoid.

    const int   u2  = (lane < kH - 128) ? (128 + lane) : (kH - 1);
    const float wo0 = Wout[lane];
    const float wo1 = Wout[64 + lane];
    const float wo2 = (128 + lane < kH) ? Wout[128 + lane] : 0.0f;
    const float bo  = bout[0];

    float vc0 = 0.f, vc1 = 0.f, vc2 = 0.f;
    float vh0 = 0.f, vh1 = 0.f, vh2 = 0.f;
    float pred = 0.f;

    float* pred_out = out + (size_t)b * kT;
    float* flag_out = out + (size_t)kB * kT + (size_t)b * kT;
    const float* xb = x + (size_t)b * kT * kI;

    float4 xa = ((const float4*)xb)[0];
    float4 xc = ((const float4*)xb)[1];

    __syncthreads();

    for (int t = 0; t < kT; ++t) {
        // prefetch x[t+1] (consumed next iter)
        const float4* nx = (const float4*)(xb + (t + 1 < kT ? (t + 1) : t) * kI);
        float4 na = nx[0];
        float4 nc = nx[1];

        const bool  anom = (t > 0) && (fabsf(pred - xa.x) > kThresh);
        const float x0e  = anom ? pred : xa.x;

        // ---- W_ih parts for the 3 rows ----
        float4 p00 = wih_p[r0], p01 = wih_p[kG + r0];
        float4 p10 = wih_p[r1], p11 = wih_p[kG + r1];
        float4 p30 = wih_p[r3], p31 = wih_p[kG + r3];
        float a0 = fmaf(x0e,  p00.x, bsum0);
        float a1 = xa.y * p00.y;
        float a2 = xa.z * p00.z;
        float a3 = xa.w * p00.w;
        a0 = fmaf(xc.x, p01.x, a0);
        a1 = fmaf(xc.y, p01.y, a1);
        a2 = fmaf(xc.z, p01.z, a2);
        a3 = fmaf(xc.w, p01.w, a3);
        float b0 = fmaf(x0e,  p10.x, bsum1);
        float b1 = xa.y * p10.y;
        float b2 = xa.z * p10.z;
        float b3 = xa.w * p10.w;
        b0 = fmaf(xc.x, p11.x, b0);
        b1 = fmaf(xc.y, p11.y, b1);
        b2 = fmaf(xc.z, p11.z, b2);
        b3 = fmaf(xc.w, p11.w, b3);
        float d0 = fmaf(x0e,  p30.x, bsum3);
        float d1 = xa.y * p30.y;
        float d2 = xa.z * p30.z;
        float d3 = xa.w * p30.w;
        d0 = fmaf(xc.x, p31.x, d0);
        d1 = fmaf(xc.y, p31.y, d1);
        d2 = fmaf(xc.z, p31.z, d2);
        d3 = fmaf(xc.w, p31.w, d3);

        // ---- k-loop: each h broadcast feeds 3 FMAs ----
        #pragma unroll
        for (int kk = 0; kk < kHC; ++kk) {
            const int k = kk * 4;
            float4 w0 = wreg0[kk];
            float4 w1 = wreg1[kk];
            float4 w3 = w2[kk * kW2 + i3];
            float h0v = hb(vh0, vh1, vh2, k + 0);
            float h1v = hb(vh0, vh1, vh2, k + 1);
            float h2v = hb(vh0, vh1, vh2, k + 2);
            float h3v = hb(vh0, vh1, vh2, k + 3);
            a0 = fmaf(h0v, w0.x, a0);  b0 = fmaf(h0v, w1.x, b0);  d0 = fmaf(h0v, w3.x, d0);
            a1 = fmaf(h1v, w0.y, a1);  b1 = fmaf(h1v, w1.y, b1);  d1 = fmaf(h1v, w3.y, d1);
            a2 = fmaf(h2v, w0.z, a2);  b2 = fmaf(h2v, w1.z, b2);  d2 = fmaf(h2v, w3.z, d2);
            a3 = fmaf(h3v, w0.w, a3);  b3 = fmaf(h3v, w1.w, b3);  d3 = fmaf(h3v, w3.w, d3);
        }

        const float acc0 = (a0 + a1) + (a2 + a3);
        const float acc1 = (b0 + b1) + (b2 + b3);
        const float acc3 = (d0 + d1) + (d2 + d3);

        const float g0 = sigm(acc0);                       // rows 0..255: i/f
        const float g1 = tanh1 ? tanh_f(acc1) : sigm(acc1);
        const float g3 = sigm(acc3);                       // o-gate tail

        float* gw = gates[t & 1];
        gw[r0] = g0;
        gw[r1] = g1;
        if (act3) gw[r3] = g3;
        __syncthreads();

        // ---- redundant cell/h update in every wave ----
        const float* gb = gates[t & 1];
        float iv0 = gb[lane],          iv1 = gb[64 + lane],          iv2 = gb[u2];
        float fv0 = gb[kH + lane],     fv1 = gb[kH + 64 + lane],     fv2 = gb[kH + u2];
        float gv0 = gb[2*kH + lane],   gv1 = gb[2*kH + 64 + lane],   gv2 = gb[2*kH + u2];
        float ov0 = gb[3*kH + lane],   ov1 = gb[3*kH + 64 + lane],   ov2 = gb[3*kH + u2];
        vc0 = fmaf(fv0, vc0, iv0 * gv0);  vh0 = ov0 * tanh_f(vc0);
        vc1 = fmaf(fv1, vc1, iv1 * gv1);  vh1 = ov1 * tanh_f(vc1);
        vc2 = fmaf(fv2, vc2, iv2 * gv2);  vh2 = ov2 * tanh_f(vc2);

        // ---- pred (identical in every wave; DPP reduce) ----
        float p = fmaf(vh0, wo0, fmaf(vh1, wo1, vh2 * wo2));
        pred = wave_sum(p) + bo;

        if (tid == 0) {
            pred_out[t] = pred;
            flag_out[t] = anom ? 1.0f : 0.0f;
        }
        xa = na;
        xc = nc;
    }
}

extern "C" void kernel_launch(void* const* d_in, const int* in_sizes, int n_in,
                              void* d_out, int out_size, void* d_ws, size_t ws_size,
                              hipStream_t stream) {
    const float* x    = (const float*)d_in[0];
    const float* Wih  = (const float*)d_in[1];
    const float* Whh  = (const float*)d_in[2];
    const float* bih  = (const float*)d_in[3];
    const float* bhh  = (const float*)d_in[4];
    const float* Wout = (const float*)d_in[5];
    const float* bout = (const float*)d_in[6];
    lstm_anom_kernel<<<dim3(kB), dim3(kThreads), 0, stream>>>(
        x, Wih, Whh, bih, bhh, Wout, bout, (float*)d_out);
}